// Round 1
// baseline (1533.570 us; speedup 1.0000x reference)
//
#include <hip/hip_runtime.h>
#include <math.h>

#define BB 32
#define TT 8
#define PP 196
#define DD 768
#define MM 10
#define NCLS 100
#define NIDX 98

// ---------------------------------------------------------------------------
// mask dtype detection: 0 = int32 {0,1}, 1 = float32 {0,1.0f}, 2 = bytes
// ---------------------------------------------------------------------------
__global__ void detect_mode(const unsigned int* __restrict__ w, int n, int* __restrict__ mode) {
    __shared__ int f_ni, f_nf;
    if (threadIdx.x == 0) { f_ni = 0; f_nf = 0; }
    __syncthreads();
    int ni = 0, nf = 0;
    for (int i = threadIdx.x; i < n; i += blockDim.x) {
        unsigned int x = w[i];
        ni |= (x > 1u) ? 1 : 0;
        nf |= (x != 0u && x != 0x3F800000u) ? 1 : 0;
    }
    if (ni) atomicOr(&f_ni, 1);
    if (nf) atomicOr(&f_nf, 1);
    __syncthreads();
    if (threadIdx.x == 0) *mode = f_ni ? (f_nf ? 2 : 1) : 0;
}

// ---------------------------------------------------------------------------
// K0: feats = tanh(causal @ Wf + bf); feats2 = causal @ Wf2 + bf2
// grid = B*M blocks, 256 threads
// ---------------------------------------------------------------------------
__global__ __launch_bounds__(256) void k_feats(
    const float* __restrict__ causal, const float* __restrict__ Wf,
    const float* __restrict__ bf, const float* __restrict__ Wf2,
    const float* __restrict__ bf2, float* __restrict__ tanhfeats,
    float* __restrict__ feats2) {
    int bm = blockIdx.x;
    __shared__ float cs[DD];
    __shared__ float red[256];
    int t = threadIdx.x;
    for (int i = t; i < DD; i += 256) cs[i] = causal[(size_t)bm * DD + i];
    __syncthreads();
    // feats2 scalar: dot(causal_row, Wf2)
    float p2 = 0.f;
    for (int k = t; k < DD; k += 256) p2 += cs[k] * Wf2[k];
    red[t] = p2;
    __syncthreads();
    for (int s = 128; s > 0; s >>= 1) {
        if (t < s) red[t] += red[t + s];
        __syncthreads();
    }
    if (t == 0) feats2[bm] = red[0] + bf2[0];
    // feats row
    for (int dd = 0; dd < 3; ++dd) {
        int d = t + dd * 256;
        float acc = bf[d];
        #pragma unroll 8
        for (int k = 0; k < DD; ++k) acc = fmaf(cs[k], Wf[(size_t)k * DD + d], acc);
        tanhfeats[(size_t)bm * DD + d] = tanhf(acc);
    }
}

// ---------------------------------------------------------------------------
// K1: fw = softmax_m(tanhfeats); ci; audio2 = cp*ci + audio;
//     pa = tanh(audio2 @ Waa + baa); af = relu(audio2 @ Wa + ba)
// grid = B blocks, 256 threads
// ---------------------------------------------------------------------------
__global__ __launch_bounds__(256) void k_audio2(
    const float* __restrict__ causal, const float* __restrict__ audio,
    const float* __restrict__ tanhfeats, const float* __restrict__ feats2,
    const float* __restrict__ cparam,
    const float* __restrict__ Waa, const float* __restrict__ baa,
    const float* __restrict__ Wa, const float* __restrict__ ba,
    float* __restrict__ pa, float* __restrict__ af) {
    int b = blockIdx.x;
    int t = threadIdx.x;
    __shared__ float a2[DD];
    float cp = 1.0f / (1.0f + __expf(-cparam[0]));
    for (int dd = 0; dd < 3; ++dd) {
        int d = t + dd * 256;
        float tf[MM];
        float mx = -1e30f;
        #pragma unroll
        for (int m = 0; m < MM; ++m) {
            tf[m] = tanhfeats[((size_t)b * MM + m) * DD + d];
            mx = fmaxf(mx, tf[m]);
        }
        float s = 0.f;
        #pragma unroll
        for (int m = 0; m < MM; ++m) { tf[m] = __expf(tf[m] - mx); s += tf[m]; }
        float inv = 1.0f / s;
        float ci = 0.f;
        #pragma unroll
        for (int m = 0; m < MM; ++m)
            ci += feats2[b * MM + m] * (tf[m] * inv) * causal[((size_t)b * MM + m) * DD + d];
        a2[d] = cp * ci + audio[(size_t)b * DD + d];
    }
    __syncthreads();
    for (int dd = 0; dd < 3; ++dd) {
        int d = t + dd * 256;
        float accp = baa[d], acca = ba[d];
        #pragma unroll 8
        for (int k = 0; k < DD; ++k) {
            float av = a2[k];
            accp = fmaf(av, Waa[(size_t)k * DD + d], accp);
            acca = fmaf(av, Wa[(size_t)k * DD + d], acca);
        }
        pa[(size_t)b * DD + d] = tanhf(accp);
        af[(size_t)b * DD + d] = fmaxf(acca, 0.f);
    }
}

// ---------------------------------------------------------------------------
// K2: pv = tanh(vis @ Wav + bav)   [50176 x 768] * [768 x 768] f32 GEMM
// 128x128 tile, BK=16, 256 threads, 8x8 micro-tile
// ---------------------------------------------------------------------------
#define BMT 128
#define BNT 128
#define BKT 16
__global__ __launch_bounds__(256) void k_pv(
    const float* __restrict__ vis, const float* __restrict__ Wav,
    const float* __restrict__ bav, float* __restrict__ pv) {
    int n0 = blockIdx.x * BNT;
    int i0 = blockIdx.y * BMT;
    __shared__ float As[BKT][BMT + 4];
    __shared__ float Bs[BKT][BNT + 4];
    int t = threadIdx.x;
    int tx = t & 15, ty = t >> 4;
    float acc[8][8];
    #pragma unroll
    for (int i = 0; i < 8; ++i)
        #pragma unroll
        for (int j = 0; j < 8; ++j) acc[i][j] = 0.f;

    for (int k0 = 0; k0 < DD; k0 += BKT) {
        #pragma unroll
        for (int f0 = 0; f0 < 2; ++f0) {
            int f = t + f0 * 256;
            int r = f >> 2, cg = f & 3;
            const float4 v = *(const float4*)(vis + (size_t)(i0 + r) * DD + k0 + cg * 4);
            As[cg * 4 + 0][r] = v.x;
            As[cg * 4 + 1][r] = v.y;
            As[cg * 4 + 2][r] = v.z;
            As[cg * 4 + 3][r] = v.w;
        }
        #pragma unroll
        for (int f0 = 0; f0 < 2; ++f0) {
            int f = t + f0 * 256;
            int r = f >> 5, cg = f & 31;
            *(float4*)&Bs[r][cg * 4] = *(const float4*)(Wav + (size_t)(k0 + r) * DD + n0 + cg * 4);
        }
        __syncthreads();
        #pragma unroll
        for (int k = 0; k < BKT; ++k) {
            float a[8], b[8];
            *(float4*)&a[0] = *(const float4*)&As[k][ty * 8];
            *(float4*)&a[4] = *(const float4*)&As[k][ty * 8 + 4];
            *(float4*)&b[0] = *(const float4*)&Bs[k][tx * 8];
            *(float4*)&b[4] = *(const float4*)&Bs[k][tx * 8 + 4];
            #pragma unroll
            for (int i = 0; i < 8; ++i)
                #pragma unroll
                for (int j = 0; j < 8; ++j) acc[i][j] = fmaf(a[i], b[j], acc[i][j]);
        }
        __syncthreads();
    }
    #pragma unroll
    for (int i = 0; i < 8; ++i) {
        int row = i0 + ty * 8 + i;
        float* orow = pv + (size_t)row * DD + n0 + tx * 8;
        float o[8];
        #pragma unroll
        for (int j = 0; j < 8; ++j) o[j] = tanhf(acc[i][j] + bav[n0 + tx * 8 + j]);
        *(float4*)&orow[0] = *(float4*)&o[0];
        *(float4*)&orow[4] = *(float4*)&o[4];
    }
}

// ---------------------------------------------------------------------------
// K3: per (b,t): spatial softmax over P, patch sums, rank-select threshold,
//     masked sums -> sav[b,t,:], vpt[b,t,:]
// grid = B*T = 256 blocks, 768 threads (one d per thread)
// ---------------------------------------------------------------------------
__global__ __launch_bounds__(768) void k_spatial(
    const float* __restrict__ pv, const float* __restrict__ vis,
    const void* __restrict__ rmask, const int* __restrict__ mode_p,
    const float* __restrict__ pa,
    float* __restrict__ sav, float* __restrict__ vpt) {
    int bt = blockIdx.x;
    int b = bt >> 3;
    size_t base = (size_t)bt * PP * DD;
    __shared__ float ms[DD], invs[DD], pas[DD];
    __shared__ float patch[PP];
    __shared__ unsigned char spa[PP];
    int t = threadIdx.x;
    int d = t;
    float pav = pa[(size_t)b * DD + d];
    pas[d] = pav;
    // pass 1: online softmax stats per column d over the 196 patches
    float mx = -1e30f, s = 0.f;
    for (int p = 0; p < PP; ++p) {
        float x = pv[base + (size_t)p * DD + d] * pav;
        float mn = fmaxf(mx, x);
        s = s * __expf(mx - mn) + __expf(x - mn);
        mx = mn;
    }
    ms[d] = mx;
    invs[d] = 1.0f / s;
    __syncthreads();
    // pass 2: patch[p] = sum_d sattn[p,d]  (wave-parallel over d)
    int wave = t >> 6, lane = t & 63;
    for (int p = wave; p < PP; p += 12) {
        float sum = 0.f;
        for (int dk = lane; dk < DD; dk += 64) {
            float x = pv[base + (size_t)p * DD + dk] * pas[dk];
            sum += __expf(x - ms[dk]) * invs[dk];
        }
        #pragma unroll
        for (int o = 32; o > 0; o >>= 1) sum += __shfl_down(sum, o);
        if (lane == 0) patch[p] = sum;
    }
    __syncthreads();
    // rank-select: spa[p] = (patch[p] < sorted(patch)[98])
    //            = (#{q: patch[q] <= patch[p]} <= 98)   (tie-exact)
    if (t < PP) {
        float x = patch[t];
        int c = 0;
        for (int q = 0; q < PP; ++q) c += (patch[q] <= x) ? 1 : 0;
        spa[t] = (c <= NIDX) ? 1 : 0;
    }
    __syncthreads();
    // pass 3: masked sums
    int mode = *mode_p;
    float mm = ms[d], inv = invs[d];
    float sava = 0.f, vpa = 0.f;
    const int* mi = (const int*)rmask;
    const float* mf = (const float*)rmask;
    const unsigned char* mb = (const unsigned char*)rmask;
    for (int p = 0; p < PP; ++p) {
        size_t idx = base + (size_t)p * DD + d;
        float pvv = pv[idx];
        float sa = __expf(pvv * pav - mm) * inv;
        bool rm;
        if (mode == 0)      rm = (mi[idx] != 0);
        else if (mode == 1) rm = (mf[idx] != 0.f);
        else                rm = (mb[idx] != 0);
        if (!(spa[p] && rm)) {
            sava = fmaf(sa, pvv, sava);
            vpa = fmaf(sa, vis[idx], vpa);
        }
    }
    sav[(size_t)bt * DD + d] = sava;
    vpt[(size_t)bt * DD + d] = vpa;
}

// ---------------------------------------------------------------------------
// K4: temporal softmax + vp; vf = relu(vp@Wv+bv); h = vf+af; logits = h@Wc+bc
// grid = B blocks, 256 threads
// ---------------------------------------------------------------------------
__global__ __launch_bounds__(256) void k_tail(
    const float* __restrict__ sav, const float* __restrict__ vpt,
    const float* __restrict__ pa, const float* __restrict__ af,
    const float* __restrict__ Wv, const float* __restrict__ bv,
    const float* __restrict__ Wc, const float* __restrict__ bc,
    float* __restrict__ out) {
    int b = blockIdx.x;
    int t = threadIdx.x;
    __shared__ float vp[DD];
    __shared__ float h[DD];
    for (int dd = 0; dd < 3; ++dd) {
        int d = t + dd * 256;
        float pav = pa[(size_t)b * DD + d];
        float x[TT];
        float mx = -1e30f;
        #pragma unroll
        for (int k = 0; k < TT; ++k) {
            x[k] = sav[((size_t)b * TT + k) * DD + d] * pav;
            mx = fmaxf(mx, x[k]);
        }
        float s = 0.f;
        #pragma unroll
        for (int k = 0; k < TT; ++k) { x[k] = __expf(x[k] - mx); s += x[k]; }
        float inv = 1.0f / s;
        float acc = 0.f;
        #pragma unroll
        for (int k = 0; k < TT; ++k)
            acc += x[k] * inv * vpt[((size_t)b * TT + k) * DD + d];
        vp[d] = acc;
    }
    __syncthreads();
    for (int dd = 0; dd < 3; ++dd) {
        int d = t + dd * 256;
        float acc = bv[d];
        #pragma unroll 8
        for (int k = 0; k < DD; ++k) acc = fmaf(vp[k], Wv[(size_t)k * DD + d], acc);
        h[d] = fmaxf(acc, 0.f) + af[(size_t)b * DD + d];
    }
    __syncthreads();
    if (t < NCLS) {
        float acc = bc[t];
        #pragma unroll 8
        for (int k = 0; k < DD; ++k) acc = fmaf(h[k], Wc[(size_t)k * NCLS + t], acc);
        out[(size_t)b * NCLS + t] = acc;
    }
}

// ---------------------------------------------------------------------------
extern "C" void kernel_launch(void* const* d_in, const int* in_sizes, int n_in,
                              void* d_out, int out_size, void* d_ws, size_t ws_size,
                              hipStream_t stream) {
    const float* visual = (const float*)d_in[0];
    const float* audio  = (const float*)d_in[1];
    const float* causal = (const float*)d_in[2];
    const void*  rmask  = d_in[3];
    const float* Wa   = (const float*)d_in[4];
    const float* ba   = (const float*)d_in[5];
    const float* Wv   = (const float*)d_in[6];
    const float* bv   = (const float*)d_in[7];
    const float* Waa  = (const float*)d_in[8];
    const float* baa  = (const float*)d_in[9];
    const float* Wav  = (const float*)d_in[10];
    const float* bav  = (const float*)d_in[11];
    const float* Wf   = (const float*)d_in[12];
    const float* bf   = (const float*)d_in[13];
    const float* Wf2  = (const float*)d_in[14];
    const float* bf2  = (const float*)d_in[15];
    const float* Wc   = (const float*)d_in[16];
    const float* bc   = (const float*)d_in[17];
    const float* cpar = (const float*)d_in[18];
    float* out = (float*)d_out;

    float* ws = (float*)d_ws;
    float* tanhfeats = ws;                                   // B*M*D = 245760
    float* feats2    = tanhfeats + (size_t)BB * MM * DD;     // 320 (pad 512)
    float* paw       = feats2 + 512;                         // B*D
    float* afw       = paw + (size_t)BB * DD;                // B*D
    float* pvw       = afw + (size_t)BB * DD;                // B*T*P*D
    float* savw      = pvw + (size_t)BB * TT * PP * DD;      // B*T*D
    float* vptw      = savw + (size_t)BB * TT * DD;          // B*T*D
    int*   modew     = (int*)(vptw + (size_t)BB * TT * DD);  // 1

    detect_mode<<<1, 256, 0, stream>>>((const unsigned int*)rmask, 16384, modew);
    k_feats<<<BB * MM, 256, 0, stream>>>(causal, Wf, bf, Wf2, bf2, tanhfeats, feats2);
    k_audio2<<<BB, 256, 0, stream>>>(causal, audio, tanhfeats, feats2, cpar,
                                     Waa, baa, Wa, ba, paw, afw);
    dim3 g2(DD / BNT, (BB * TT * PP) / BMT);
    k_pv<<<g2, 256, 0, stream>>>(visual, Wav, bav, pvw);
    k_spatial<<<BB * TT, 768, 0, stream>>>(pvw, visual, rmask, modew, paw, savw, vptw);
    k_tail<<<BB, 256, 0, stream>>>(savw, vptw, paw, afw, Wv, bv, Wc, bc, out);
}

// Round 2
// 1142.542 us; speedup vs baseline: 1.3422x; 1.3422x over previous
//
#include <hip/hip_runtime.h>
#include <math.h>

#define BB 32
#define TT 8
#define PP 196
#define DD 768
#define MM 10
#define NCLS 100
#define NIDX 98

typedef __attribute__((ext_vector_type(8))) short short8v;
typedef __attribute__((ext_vector_type(4))) float float4v;

__device__ __forceinline__ float fast_tanh(float x) {
    float e = __expf(2.0f * x);
    return 1.0f - 2.0f / (e + 1.0f);
}
__device__ __forceinline__ unsigned short bf16_rtne(float x) {
    unsigned u = __float_as_uint(x);
    return (unsigned short)((u + 0x7FFFu + ((u >> 16) & 1u)) >> 16);
}
__device__ __forceinline__ float bf16_tof(unsigned short h) {
    return __uint_as_float(((unsigned)h) << 16);
}

// ---------------------------------------------------------------------------
// mask dtype detection: 0 = int32 {0,1}, 1 = float32 {0,1.0f}, 2 = bytes
// ---------------------------------------------------------------------------
__global__ void detect_mode(const unsigned int* __restrict__ w, int n, int* __restrict__ mode) {
    __shared__ int f_ni, f_nf;
    if (threadIdx.x == 0) { f_ni = 0; f_nf = 0; }
    __syncthreads();
    int ni = 0, nf = 0;
    for (int i = threadIdx.x; i < n; i += blockDim.x) {
        unsigned int x = w[i];
        ni |= (x > 1u) ? 1 : 0;
        nf |= (x != 0u && x != 0x3F800000u) ? 1 : 0;
    }
    if (ni) atomicOr(&f_ni, 1);
    if (nf) atomicOr(&f_nf, 1);
    __syncthreads();
    if (threadIdx.x == 0) *mode = f_ni ? (f_nf ? 2 : 1) : 0;
}

// ---------------------------------------------------------------------------
// Wav split+transpose: Wht/Wlt[n][k] bf16 (hi = trunc, lo = rtne(residual))
// grid (24,24), 256 threads
// ---------------------------------------------------------------------------
__global__ __launch_bounds__(256) void k_split_w(const float* __restrict__ W,
    unsigned short* __restrict__ ht, unsigned short* __restrict__ lt) {
    __shared__ float tile[32][33];
    int bn = blockIdx.x * 32;
    int bk = blockIdx.y * 32;
    int tx = threadIdx.x & 31, ty = threadIdx.x >> 5;
    #pragma unroll
    for (int i = 0; i < 4; ++i)
        tile[ty + i * 8][tx] = W[(size_t)(bk + ty + i * 8) * DD + bn + tx];
    __syncthreads();
    #pragma unroll
    for (int i = 0; i < 4; ++i) {
        int n = bn + ty + i * 8, k = bk + tx;
        float x = tile[tx][ty + i * 8];
        unsigned short h = (unsigned short)(__float_as_uint(x) >> 16);
        ht[(size_t)n * DD + k] = h;
        lt[(size_t)n * DD + k] = bf16_rtne(x - bf16_tof(h));
    }
}

// ---------------------------------------------------------------------------
// K0: feats = tanh(causal @ Wf + bf); feats2 = causal @ Wf2 + bf2
// ---------------------------------------------------------------------------
__global__ __launch_bounds__(256) void k_feats(
    const float* __restrict__ causal, const float* __restrict__ Wf,
    const float* __restrict__ bf, const float* __restrict__ Wf2,
    const float* __restrict__ bf2, float* __restrict__ tanhfeats,
    float* __restrict__ feats2) {
    int bm = blockIdx.x;
    __shared__ float cs[DD];
    __shared__ float red[256];
    int t = threadIdx.x;
    for (int i = t; i < DD; i += 256) cs[i] = causal[(size_t)bm * DD + i];
    __syncthreads();
    float p2 = 0.f;
    for (int k = t; k < DD; k += 256) p2 += cs[k] * Wf2[k];
    red[t] = p2;
    __syncthreads();
    for (int s = 128; s > 0; s >>= 1) {
        if (t < s) red[t] += red[t + s];
        __syncthreads();
    }
    if (t == 0) feats2[bm] = red[0] + bf2[0];
    for (int dd = 0; dd < 3; ++dd) {
        int d = t + dd * 256;
        float acc = bf[d];
        #pragma unroll 8
        for (int k = 0; k < DD; ++k) acc = fmaf(cs[k], Wf[(size_t)k * DD + d], acc);
        tanhfeats[(size_t)bm * DD + d] = fast_tanh(acc);
    }
}

// ---------------------------------------------------------------------------
// K1: softmax_m, ci, audio2, pa, af
// ---------------------------------------------------------------------------
__global__ __launch_bounds__(256) void k_audio2(
    const float* __restrict__ causal, const float* __restrict__ audio,
    const float* __restrict__ tanhfeats, const float* __restrict__ feats2,
    const float* __restrict__ cparam,
    const float* __restrict__ Waa, const float* __restrict__ baa,
    const float* __restrict__ Wa, const float* __restrict__ ba,
    float* __restrict__ pa, float* __restrict__ af) {
    int b = blockIdx.x;
    int t = threadIdx.x;
    __shared__ float a2[DD];
    float cp = 1.0f / (1.0f + __expf(-cparam[0]));
    for (int dd = 0; dd < 3; ++dd) {
        int d = t + dd * 256;
        float tf[MM];
        float mx = -1e30f;
        #pragma unroll
        for (int m = 0; m < MM; ++m) {
            tf[m] = tanhfeats[((size_t)b * MM + m) * DD + d];
            mx = fmaxf(mx, tf[m]);
        }
        float s = 0.f;
        #pragma unroll
        for (int m = 0; m < MM; ++m) { tf[m] = __expf(tf[m] - mx); s += tf[m]; }
        float inv = 1.0f / s;
        float ci = 0.f;
        #pragma unroll
        for (int m = 0; m < MM; ++m)
            ci += feats2[b * MM + m] * (tf[m] * inv) * causal[((size_t)b * MM + m) * DD + d];
        a2[d] = cp * ci + audio[(size_t)b * DD + d];
    }
    __syncthreads();
    for (int dd = 0; dd < 3; ++dd) {
        int d = t + dd * 256;
        float accp = baa[d], acca = ba[d];
        #pragma unroll 8
        for (int k = 0; k < DD; ++k) {
            float av = a2[k];
            accp = fmaf(av, Waa[(size_t)k * DD + d], accp);
            acca = fmaf(av, Wa[(size_t)k * DD + d], acca);
        }
        pa[(size_t)b * DD + d] = fast_tanh(accp);
        af[(size_t)b * DD + d] = fmaxf(acca, 0.f);
    }
}

// ---------------------------------------------------------------------------
// K2: pv = tanh(vis @ Wav + bav) via split-bf16 MFMA.
// C = Ah*Wh + Ah*Wl + Al*Wh. 128x128 tile, 64-K windows x 3 phases.
// A reg-staged from f32 (split on the fly), B via global_load_lds from Wht/Wlt.
// XOR swizzle (chunk ^= row&7) on LDS for conflict-free ds_read_b128.
// ---------------------------------------------------------------------------
__global__ __launch_bounds__(256) void k_pv_mfma(
    const float* __restrict__ vis, const unsigned short* __restrict__ Wht,
    const unsigned short* __restrict__ Wlt, const float* __restrict__ bav,
    float* __restrict__ pv)
{
    __shared__ unsigned short As[128 * 64];
    __shared__ unsigned short Bs[128 * 64];
    int wg = blockIdx.x;
    int lin = (wg & 7) * 294 + (wg >> 3);   // bijective XCD swizzle (2352%8==0)
    int mt = lin / 6, nt = lin % 6;
    int i0 = mt * 128, n0 = nt * 128;
    int t = threadIdx.x, w = t >> 6, l = t & 63;
    int wm = (w >> 1) * 64, wn = (w & 1) * 64;

    float4v zero4 = {0.f, 0.f, 0.f, 0.f};
    float4v acc[4][4];
    #pragma unroll
    for (int a = 0; a < 4; ++a)
        #pragma unroll
        for (int b = 0; b < 4; ++b) acc[a][b] = zero4;

    // B staging: call j covers LDS bytes [(w*4+j)*1024, +1024); lane l at +l*16
    int brow[4], bcs[4];
    #pragma unroll
    for (int j = 0; j < 4; ++j) {
        int row = (w * 4 + j) * 8 + (l >> 3);
        brow[j] = row;
        bcs[j] = (l & 7) ^ (row & 7);      // pre-swizzled source chunk
    }
    // A staging: thread t covers row t>>1, chunks (t&1)*4 .. +3
    int arow = t >> 1;
    int acb = (t & 1) * 4;
    const float* avbase = vis + (size_t)(i0 + arow) * DD + acb * 8;
    unsigned short* adst[4];
    #pragma unroll
    for (int c4 = 0; c4 < 4; ++c4) {
        int c = acb + c4;
        adst[c4] = &As[arow * 64 + ((c ^ (arow & 7)) * 8)];
    }

    for (int s = 0; s < 36; ++s) {
        int window = s / 3, ph = s - window * 3;   // ph: 0=Ah*Wh 1=Ah*Wl 2=Al*Wh
        int kw = window * 64;
        __syncthreads();   // protect LDS overwrite from previous compute
        const unsigned short* bS = (ph == 1) ? Wlt : Wht;
        #pragma unroll
        for (int j = 0; j < 4; ++j) {
            const unsigned short* g = bS + (size_t)(n0 + brow[j]) * DD + kw + bcs[j] * 8;
            __builtin_amdgcn_global_load_lds(
                (const __attribute__((address_space(1))) unsigned int*)g,
                (__attribute__((address_space(3))) unsigned int*)&Bs[(w * 4 + j) * 512],
                16, 0, 0);
        }
        if (ph != 1) {
            float f[32];
            const float* ap = avbase + kw;
            #pragma unroll
            for (int q = 0; q < 8; ++q)
                *(float4*)&f[q * 4] = *(const float4*)(ap + q * 4);
            unsigned short hv[32];
            if (ph == 0) {
                #pragma unroll
                for (int i = 0; i < 32; ++i)
                    hv[i] = (unsigned short)(__float_as_uint(f[i]) >> 16);
            } else {
                #pragma unroll
                for (int i = 0; i < 32; ++i) {
                    unsigned short h = (unsigned short)(__float_as_uint(f[i]) >> 16);
                    hv[i] = bf16_rtne(f[i] - bf16_tof(h));
                }
            }
            #pragma unroll
            for (int c4 = 0; c4 < 4; ++c4)
                *(short8v*)adst[c4] = *(const short8v*)&hv[c4 * 8];
        }
        __syncthreads();   // staging visible (vmcnt+lgkm drained by barrier)
        #pragma unroll
        for (int kk = 0; kk < 2; ++kk) {
            short8v af4[4], bf4[4];
            #pragma unroll
            for (int mr = 0; mr < 4; ++mr) {
                int row = wm + mr * 16 + (l & 15);
                int c = kk * 4 + (l >> 4);
                af4[mr] = *(const short8v*)&As[row * 64 + ((c ^ (row & 7)) * 8)];
            }
            #pragma unroll
            for (int nc = 0; nc < 4; ++nc) {
                int row = wn + nc * 16 + (l & 15);
                int c = kk * 4 + (l >> 4);
                bf4[nc] = *(const short8v*)&Bs[row * 64 + ((c ^ (row & 7)) * 8)];
            }
            #pragma unroll
            for (int mr = 0; mr < 4; ++mr)
                #pragma unroll
                for (int nc = 0; nc < 4; ++nc)
                    acc[mr][nc] = __builtin_amdgcn_mfma_f32_16x16x32_bf16(
                        af4[mr], bf4[nc], acc[mr][nc], 0, 0, 0);
        }
    }
    // epilogue: C[row][col], col = lane&15, row = (lane>>4)*4 + v  (m89 layout)
    #pragma unroll
    for (int nc = 0; nc < 4; ++nc) {
        int col = n0 + wn + nc * 16 + (l & 15);
        float bias = bav[col];
        #pragma unroll
        for (int mr = 0; mr < 4; ++mr) {
            int row0 = i0 + wm + mr * 16 + ((l >> 4) << 2);
            #pragma unroll
            for (int v = 0; v < 4; ++v)
                pv[(size_t)(row0 + v) * DD + col] = fast_tanh(acc[mr][nc][v] + bias);
        }
    }
}

// ---------------------------------------------------------------------------
// K3: per (b,t): spatial softmax (no max needed: |pv*pa|<1), patch sums,
// rank-select threshold, masked sums
// ---------------------------------------------------------------------------
__global__ __launch_bounds__(768) void k_spatial(
    const float* __restrict__ pv, const float* __restrict__ vis,
    const void* __restrict__ rmask, const int* __restrict__ mode_p,
    const float* __restrict__ pa,
    float* __restrict__ sav, float* __restrict__ vpt) {
    int bt = blockIdx.x;
    int b = bt >> 3;
    size_t base = (size_t)bt * PP * DD;
    __shared__ float invs[DD], pas[DD];
    __shared__ float patch[PP];
    __shared__ unsigned char spa[PP];
    int t = threadIdx.x;
    int d = t;
    float pav = pa[(size_t)b * DD + d];
    pas[d] = pav;
    // pass 1: s_d = sum_p exp(pv*pav)   (no max: |x|<1)
    float s = 0.f;
    #pragma unroll 4
    for (int p = 0; p < PP; ++p)
        s += __expf(pv[base + (size_t)p * DD + d] * pav);
    float inv = 1.0f / s;
    invs[d] = inv;
    __syncthreads();
    // pass 2: patch[p] = sum_d sattn[p,d]
    int wave = t >> 6, lane = t & 63;
    for (int p = wave; p < PP; p += 12) {
        float sum = 0.f;
        #pragma unroll 4
        for (int dk = lane; dk < DD; dk += 64)
            sum += __expf(pv[base + (size_t)p * DD + dk] * pas[dk]) * invs[dk];
        #pragma unroll
        for (int o = 32; o > 0; o >>= 1) sum += __shfl_down(sum, o);
        if (lane == 0) patch[p] = sum;
    }
    __syncthreads();
    // rank-select: spa[p] = (#{q: patch[q] <= patch[p]} <= 98)
    if (t < PP) {
        float x = patch[t];
        int c = 0;
        for (int q = 0; q < PP; ++q) c += (patch[q] <= x) ? 1 : 0;
        spa[t] = (c <= NIDX) ? 1 : 0;
    }
    __syncthreads();
    // pass 3: masked sums
    int mode = *mode_p;
    float sava = 0.f, vpa = 0.f;
    const int* mi = (const int*)rmask;
    const float* mf = (const float*)rmask;
    const unsigned char* mb = (const unsigned char*)rmask;
    #pragma unroll 2
    for (int p = 0; p < PP; ++p) {
        size_t idx = base + (size_t)p * DD + d;
        float pvv = pv[idx];
        float sa = __expf(pvv * pav) * inv;
        bool rm;
        if (mode == 0)      rm = (mi[idx] != 0);
        else if (mode == 1) rm = (mf[idx] != 0.f);
        else                rm = (mb[idx] != 0);
        if (!(spa[p] && rm)) {
            sava = fmaf(sa, pvv, sava);
            vpa = fmaf(sa, vis[idx], vpa);
        }
    }
    sav[(size_t)bt * DD + d] = sava;
    vpt[(size_t)bt * DD + d] = vpa;
}

// ---------------------------------------------------------------------------
// K4: temporal softmax + vp; vf; logits
// ---------------------------------------------------------------------------
__global__ __launch_bounds__(256) void k_tail(
    const float* __restrict__ sav, const float* __restrict__ vpt,
    const float* __restrict__ pa, const float* __restrict__ af,
    const float* __restrict__ Wv, const float* __restrict__ bv,
    const float* __restrict__ Wc, const float* __restrict__ bc,
    float* __restrict__ out) {
    int b = blockIdx.x;
    int t = threadIdx.x;
    __shared__ float vp[DD];
    __shared__ float h[DD];
    for (int dd = 0; dd < 3; ++dd) {
        int d = t + dd * 256;
        float pav = pa[(size_t)b * DD + d];
        float x[TT];
        float mx = -1e30f;
        #pragma unroll
        for (int k = 0; k < TT; ++k) {
            x[k] = sav[((size_t)b * TT + k) * DD + d] * pav;
            mx = fmaxf(mx, x[k]);
        }
        float s = 0.f;
        #pragma unroll
        for (int k = 0; k < TT; ++k) { x[k] = __expf(x[k] - mx); s += x[k]; }
        float inv = 1.0f / s;
        float acc = 0.f;
        #pragma unroll
        for (int k = 0; k < TT; ++k)
            acc += x[k] * inv * vpt[((size_t)b * TT + k) * DD + d];
        vp[d] = acc;
    }
    __syncthreads();
    for (int dd = 0; dd < 3; ++dd) {
        int d = t + dd * 256;
        float acc = bv[d];
        #pragma unroll 8
        for (int k = 0; k < DD; ++k) acc = fmaf(vp[k], Wv[(size_t)k * DD + d], acc);
        h[d] = fmaxf(acc, 0.f) + af[(size_t)b * DD + d];
    }
    __syncthreads();
    if (t < NCLS) {
        float acc = bc[t];
        #pragma unroll 8
        for (int k = 0; k < DD; ++k) acc = fmaf(h[k], Wc[(size_t)k * NCLS + t], acc);
        out[(size_t)b * NCLS + t] = acc;
    }
}

// ---------------------------------------------------------------------------
extern "C" void kernel_launch(void* const* d_in, const int* in_sizes, int n_in,
                              void* d_out, int out_size, void* d_ws, size_t ws_size,
                              hipStream_t stream) {
    const float* visual = (const float*)d_in[0];
    const float* audio  = (const float*)d_in[1];
    const float* causal = (const float*)d_in[2];
    const void*  rmask  = d_in[3];
    const float* Wa   = (const float*)d_in[4];
    const float* ba   = (const float*)d_in[5];
    const float* Wv   = (const float*)d_in[6];
    const float* bv   = (const float*)d_in[7];
    const float* Waa  = (const float*)d_in[8];
    const float* baa  = (const float*)d_in[9];
    const float* Wav  = (const float*)d_in[10];
    const float* bav  = (const float*)d_in[11];
    const float* Wf   = (const float*)d_in[12];
    const float* bf   = (const float*)d_in[13];
    const float* Wf2  = (const float*)d_in[14];
    const float* bf2  = (const float*)d_in[15];
    const float* Wc   = (const float*)d_in[16];
    const float* bc   = (const float*)d_in[17];
    const float* cpar = (const float*)d_in[18];
    float* out = (float*)d_out;

    unsigned short* Wht = (unsigned short*)d_ws;             // 768*768 bf16
    unsigned short* Wlt = Wht + (size_t)DD * DD;             // 768*768 bf16
    float* tanhfeats = (float*)(Wlt + (size_t)DD * DD);      // B*M*D
    float* feats2    = tanhfeats + (size_t)BB * MM * DD;     // 320 (pad 512)
    float* paw       = feats2 + 512;                         // B*D
    float* afw       = paw + (size_t)BB * DD;                // B*D
    float* pvw       = afw + (size_t)BB * DD;                // B*T*P*D
    float* savw      = pvw + (size_t)BB * TT * PP * DD;      // B*T*D
    float* vptw      = savw + (size_t)BB * TT * DD;          // B*T*D
    int*   modew     = (int*)(vptw + (size_t)BB * TT * DD);  // 1

    detect_mode<<<1, 256, 0, stream>>>((const unsigned int*)rmask, 16384, modew);
    k_split_w<<<dim3(24, 24), 256, 0, stream>>>(Wav, Wht, Wlt);
    k_feats<<<BB * MM, 256, 0, stream>>>(causal, Wf, bf, Wf2, bf2, tanhfeats, feats2);
    k_audio2<<<BB, 256, 0, stream>>>(causal, audio, tanhfeats, feats2, cpar,
                                     Waa, baa, Wa, ba, paw, afw);
    k_pv_mfma<<<2352, 256, 0, stream>>>(visual, Wht, Wlt, bav, pvw);
    k_spatial<<<BB * TT, 768, 0, stream>>>(pvw, visual, rmask, modew, paw, savw, vptw);
    k_tail<<<BB, 256, 0, stream>>>(savw, vptw, paw, afw, Wv, bv, Wc, bc, out);
}

// Round 3
// 755.207 us; speedup vs baseline: 2.0307x; 1.5129x over previous
//
#include <hip/hip_runtime.h>
#include <math.h>

#define BB 32
#define TT 8
#define PP 196
#define DD 768
#define MM 10
#define NCLS 100
#define NIDX 98

typedef __attribute__((ext_vector_type(8))) short short8v;
typedef __attribute__((ext_vector_type(4))) float float4v;

__device__ __forceinline__ float fast_tanh(float x) {
    float e = __expf(2.0f * x);
    return 1.0f - 2.0f / (e + 1.0f);
}
__device__ __forceinline__ unsigned short bf16_rtne(float x) {
    unsigned u = __float_as_uint(x);
    return (unsigned short)((u + 0x7FFFu + ((u >> 16) & 1u)) >> 16);
}
__device__ __forceinline__ float bf16_tof(unsigned short h) {
    return __uint_as_float(((unsigned)h) << 16);
}

// ---------------------------------------------------------------------------
// mask dtype detection: 0 = int32 {0,1}, 1 = float32 {0,1.0f}, 2 = bytes
// ---------------------------------------------------------------------------
__global__ void detect_mode(const unsigned int* __restrict__ w, int n, int* __restrict__ mode) {
    __shared__ int f_ni, f_nf;
    if (threadIdx.x == 0) { f_ni = 0; f_nf = 0; }
    __syncthreads();
    int ni = 0, nf = 0;
    for (int i = threadIdx.x; i < n; i += blockDim.x) {
        unsigned int x = w[i];
        ni |= (x > 1u) ? 1 : 0;
        nf |= (x != 0u && x != 0x3F800000u) ? 1 : 0;
    }
    if (ni) atomicOr(&f_ni, 1);
    if (nf) atomicOr(&f_nf, 1);
    __syncthreads();
    if (threadIdx.x == 0) *mode = f_ni ? (f_nf ? 2 : 1) : 0;
}

// ---------------------------------------------------------------------------
// Wav split+transpose: Wht/Wlt[n][k] bf16 (hi = trunc, lo = rtne(residual))
// ---------------------------------------------------------------------------
__global__ __launch_bounds__(256) void k_split_w(const float* __restrict__ W,
    unsigned short* __restrict__ ht, unsigned short* __restrict__ lt) {
    __shared__ float tile[32][33];
    int bn = blockIdx.x * 32;
    int bk = blockIdx.y * 32;
    int tx = threadIdx.x & 31, ty = threadIdx.x >> 5;
    #pragma unroll
    for (int i = 0; i < 4; ++i)
        tile[ty + i * 8][tx] = W[(size_t)(bk + ty + i * 8) * DD + bn + tx];
    __syncthreads();
    #pragma unroll
    for (int i = 0; i < 4; ++i) {
        int n = bn + ty + i * 8, k = bk + tx;
        float x = tile[tx][ty + i * 8];
        unsigned short h = (unsigned short)(__float_as_uint(x) >> 16);
        ht[(size_t)n * DD + k] = h;
        lt[(size_t)n * DD + k] = bf16_rtne(x - bf16_tof(h));
    }
}

// ---------------------------------------------------------------------------
// K0: feats = tanh(causal @ Wf + bf); feats2 = causal @ Wf2 + bf2
// grid (B, 3): m-groups {3,3,4}, 768 threads (one d per thread)
// ---------------------------------------------------------------------------
__global__ __launch_bounds__(768) void k_feats(
    const float* __restrict__ causal, const float* __restrict__ Wf,
    const float* __restrict__ bf, const float* __restrict__ Wf2,
    const float* __restrict__ bf2, float* __restrict__ tanhfeats,
    float* __restrict__ feats2) {
    int b = blockIdx.x;
    int m0 = blockIdx.y * 3;
    int mcnt = (blockIdx.y == 2) ? 4 : 3;
    int t = threadIdx.x;
    __shared__ float cs[4][DD];
    __shared__ float red[4][12];
    for (int m = 0; m < mcnt; ++m)
        cs[m][t] = causal[((size_t)b * MM + m0 + m) * DD + t];
    if (mcnt == 3) cs[3][t] = 0.f;
    __syncthreads();
    float w2 = Wf2[t];
    int wave = t >> 6, lane = t & 63;
    for (int m = 0; m < mcnt; ++m) {
        float p = cs[m][t] * w2;
        #pragma unroll
        for (int o = 32; o > 0; o >>= 1) p += __shfl_down(p, o);
        if (lane == 0) red[m][wave] = p;
    }
    __syncthreads();
    if (t < mcnt) {
        float s = 0.f;
        #pragma unroll
        for (int wv = 0; wv < 12; ++wv) s += red[t][wv];
        feats2[b * MM + m0 + t] = s + bf2[0];
    }
    float acc[4];
    #pragma unroll
    for (int m = 0; m < 4; ++m) acc[m] = bf[t];
    #pragma unroll 4
    for (int k = 0; k < DD; ++k) {
        float wv = Wf[(size_t)k * DD + t];
        #pragma unroll
        for (int m = 0; m < 4; ++m) acc[m] = fmaf(cs[m][k], wv, acc[m]);
    }
    for (int m = 0; m < mcnt; ++m)
        tanhfeats[((size_t)b * MM + m0 + m) * DD + t] = fast_tanh(acc[m]);
}

// ---------------------------------------------------------------------------
// K1: softmax_m, ci, audio2, pa, af.  grid B, 768 threads (one d per thread)
// ---------------------------------------------------------------------------
__global__ __launch_bounds__(768) void k_audio2(
    const float* __restrict__ causal, const float* __restrict__ audio,
    const float* __restrict__ tanhfeats, const float* __restrict__ feats2,
    const float* __restrict__ cparam,
    const float* __restrict__ Waa, const float* __restrict__ baa,
    const float* __restrict__ Wa, const float* __restrict__ ba,
    float* __restrict__ pa, float* __restrict__ af) {
    int b = blockIdx.x;
    int t = threadIdx.x;
    __shared__ float a2[DD];
    float cp = 1.0f / (1.0f + __expf(-cparam[0]));
    float tf[MM];
    float mx = -1e30f;
    #pragma unroll
    for (int m = 0; m < MM; ++m) {
        tf[m] = tanhfeats[((size_t)b * MM + m) * DD + t];
        mx = fmaxf(mx, tf[m]);
    }
    float s = 0.f;
    #pragma unroll
    for (int m = 0; m < MM; ++m) { tf[m] = __expf(tf[m] - mx); s += tf[m]; }
    float inv = 1.0f / s;
    float ci = 0.f;
    #pragma unroll
    for (int m = 0; m < MM; ++m)
        ci += feats2[b * MM + m] * (tf[m] * inv) * causal[((size_t)b * MM + m) * DD + t];
    a2[t] = cp * ci + audio[(size_t)b * DD + t];
    __syncthreads();
    float accp = baa[t], acca = ba[t];
    #pragma unroll 4
    for (int k = 0; k < DD; ++k) {
        float av = a2[k];
        accp = fmaf(av, Waa[(size_t)k * DD + t], accp);
        acca = fmaf(av, Wa[(size_t)k * DD + t], acca);
    }
    pa[(size_t)b * DD + t] = fast_tanh(accp);
    af[(size_t)b * DD + t] = fmaxf(acca, 0.f);
}

// ---------------------------------------------------------------------------
// K2: pv16 = bf16(tanh(vis @ Wav + bav)) via split-bf16 MFMA.
// Per 64-K window: stage {Ah,Al,Bh,Bl} once -> barrier -> 96 MFMA.
// A f32 for next window prefetched into regs during MFMAs.
// ---------------------------------------------------------------------------
__global__ __launch_bounds__(256, 2) void k_pv_mfma(
    const float* __restrict__ vis, const unsigned short* __restrict__ Wht,
    const unsigned short* __restrict__ Wlt, const float* __restrict__ bav,
    unsigned short* __restrict__ pv16)
{
    __shared__ unsigned short Ah[128 * 64];
    __shared__ unsigned short Al[128 * 64];
    __shared__ unsigned short Bh[128 * 64];
    __shared__ unsigned short Bl[128 * 64];
    int wg = blockIdx.x;
    int lin = (wg & 7) * 294 + (wg >> 3);   // bijective XCD swizzle (2352%8==0)
    int mt = lin / 6, nt = lin % 6;
    int i0 = mt * 128, n0 = nt * 128;
    int t = threadIdx.x, w = t >> 6, l = t & 63;
    int wm = (w >> 1) * 64, wn = (w & 1) * 64;

    float4v zero4 = {0.f, 0.f, 0.f, 0.f};
    float4v acc[4][4];
    #pragma unroll
    for (int a = 0; a < 4; ++a)
        #pragma unroll
        for (int b = 0; b < 4; ++b) acc[a][b] = zero4;

    // B staging geometry (validated r2): call j covers rows (w*4+j)*8+(l>>3)
    int brow[4], bcs[4];
    #pragma unroll
    for (int j = 0; j < 4; ++j) {
        int row = (w * 4 + j) * 8 + (l >> 3);
        brow[j] = row;
        bcs[j] = (l & 7) ^ (row & 7);
    }
    // A staging: thread t covers row t>>1, chunks (t&1)*4..+3
    int arow = t >> 1, acb = (t & 1) * 4;
    const float* avbase = vis + (size_t)(i0 + arow) * DD + acb * 8;
    int aoff[4];
    #pragma unroll
    for (int c4 = 0; c4 < 4; ++c4) {
        int c = acb + c4;
        aoff[c4] = arow * 64 + ((c ^ (arow & 7)) * 8);
    }

    float f[32];
    #pragma unroll
    for (int q = 0; q < 8; ++q)
        *(float4*)&f[q * 4] = *(const float4*)(avbase + q * 4);

    for (int wnd = 0; wnd < 12; ++wnd) {
        __syncthreads();   // previous window's compute done; LDS reusable
        // split A regs -> Ah/Al
        unsigned short hv[32], lv[32];
        #pragma unroll
        for (int i = 0; i < 32; ++i) {
            unsigned short h = (unsigned short)(__float_as_uint(f[i]) >> 16);
            hv[i] = h;
            lv[i] = bf16_rtne(f[i] - bf16_tof(h));
        }
        #pragma unroll
        for (int c4 = 0; c4 < 4; ++c4) {
            *(short8v*)&Ah[aoff[c4]] = *(const short8v*)&hv[c4 * 8];
            *(short8v*)&Al[aoff[c4]] = *(const short8v*)&lv[c4 * 8];
        }
        int kw = wnd * 64;
        #pragma unroll
        for (int j = 0; j < 4; ++j) {
            size_t off = (size_t)(n0 + brow[j]) * DD + kw + bcs[j] * 8;
            __builtin_amdgcn_global_load_lds(
                (const __attribute__((address_space(1))) unsigned int*)(Wht + off),
                (__attribute__((address_space(3))) unsigned int*)&Bh[(w * 4 + j) * 512],
                16, 0, 0);
            __builtin_amdgcn_global_load_lds(
                (const __attribute__((address_space(1))) unsigned int*)(Wlt + off),
                (__attribute__((address_space(3))) unsigned int*)&Bl[(w * 4 + j) * 512],
                16, 0, 0);
        }
        __syncthreads();   // compiler drains vmcnt+lgkmcnt before barrier
        // prefetch next window's A f32 into regs (hidden under MFMAs)
        if (wnd < 11) {
            const float* ap = avbase + (wnd + 1) * 64;
            #pragma unroll
            for (int q = 0; q < 8; ++q)
                *(float4*)&f[q * 4] = *(const float4*)(ap + q * 4);
        }
        #pragma unroll
        for (int kk = 0; kk < 2; ++kk) {
            short8v ahf[4], alf[4], bhf[4], blf[4];
            #pragma unroll
            for (int mr = 0; mr < 4; ++mr) {
                int row = wm + mr * 16 + (l & 15);
                int c = kk * 4 + (l >> 4);
                int off = row * 64 + ((c ^ (row & 7)) * 8);
                ahf[mr] = *(const short8v*)&Ah[off];
                alf[mr] = *(const short8v*)&Al[off];
            }
            #pragma unroll
            for (int nc = 0; nc < 4; ++nc) {
                int row = wn + nc * 16 + (l & 15);
                int c = kk * 4 + (l >> 4);
                int off = row * 64 + ((c ^ (row & 7)) * 8);
                bhf[nc] = *(const short8v*)&Bh[off];
                blf[nc] = *(const short8v*)&Bl[off];
            }
            #pragma unroll
            for (int mr = 0; mr < 4; ++mr)
                #pragma unroll
                for (int nc = 0; nc < 4; ++nc) {
                    acc[mr][nc] = __builtin_amdgcn_mfma_f32_16x16x32_bf16(
                        ahf[mr], bhf[nc], acc[mr][nc], 0, 0, 0);
                    acc[mr][nc] = __builtin_amdgcn_mfma_f32_16x16x32_bf16(
                        ahf[mr], blf[nc], acc[mr][nc], 0, 0, 0);
                    acc[mr][nc] = __builtin_amdgcn_mfma_f32_16x16x32_bf16(
                        alf[mr], bhf[nc], acc[mr][nc], 0, 0, 0);
                }
        }
    }
    // epilogue: col = lane&15 (+16nc), row = (lane>>4)*4 + v (+16mr)
    #pragma unroll
    for (int nc = 0; nc < 4; ++nc) {
        int col = n0 + wn + nc * 16 + (l & 15);
        float bias = bav[col];
        #pragma unroll
        for (int mr = 0; mr < 4; ++mr) {
            int row0 = i0 + wm + mr * 16 + ((l >> 4) << 2);
            #pragma unroll
            for (int v = 0; v < 4; ++v)
                pv16[(size_t)(row0 + v) * DD + col] =
                    bf16_rtne(fast_tanh(acc[mr][nc][v] + bias));
        }
    }
}

// ---------------------------------------------------------------------------
// K3: per (b,t): spatial softmax (no max: |pv*pa|<1), patch sums, rank-select,
// masked sums. 384 threads, 2 d per thread, bf16 pv.
// ---------------------------------------------------------------------------
__global__ __launch_bounds__(384) void k_spatial(
    const unsigned short* __restrict__ pv16, const float* __restrict__ vis,
    const void* __restrict__ rmask, const int* __restrict__ mode_p,
    const float* __restrict__ pa,
    float* __restrict__ sav, float* __restrict__ vpt) {
    int bt = blockIdx.x;
    int b = bt >> 3;
    size_t base = (size_t)bt * PP * DD;
    __shared__ float invs[DD], pas[DD];
    __shared__ float patch[PP];
    __shared__ unsigned char spa[PP];
    int t = threadIdx.x;
    int d0 = 2 * t;
    float2 pp = *(const float2*)&pa[(size_t)b * DD + d0];
    float pa0 = pp.x, pa1 = pp.y;
    pas[d0] = pa0; pas[d0 + 1] = pa1;
    const unsigned short* pvb = pv16 + base + d0;
    // pass 1: column sums
    float s0 = 0.f, s1 = 0.f;
    #pragma unroll 4
    for (int p = 0; p < PP; ++p) {
        unsigned v = *(const unsigned*)(pvb + (size_t)p * DD);
        s0 += __expf(bf16_tof((unsigned short)(v & 0xFFFFu)) * pa0);
        s1 += __expf(bf16_tof((unsigned short)(v >> 16)) * pa1);
    }
    float inv0 = 1.0f / s0, inv1 = 1.0f / s1;
    invs[d0] = inv0; invs[d0 + 1] = inv1;
    __syncthreads();
    // pass 2: patch[p] = sum_d sattn[p,d]
    int wave = t >> 6, lane = t & 63;
    for (int p = wave; p < PP; p += 6) {
        const unsigned short* row = pv16 + base + (size_t)p * DD;
        float sum = 0.f;
        #pragma unroll
        for (int c = lane; c < 384; c += 64) {
            unsigned v = *(const unsigned*)(row + 2 * c);
            sum += __expf(bf16_tof((unsigned short)(v & 0xFFFFu)) * pas[2 * c]) * invs[2 * c]
                 + __expf(bf16_tof((unsigned short)(v >> 16)) * pas[2 * c + 1]) * invs[2 * c + 1];
        }
        #pragma unroll
        for (int o = 32; o > 0; o >>= 1) sum += __shfl_down(sum, o);
        if (lane == 0) patch[p] = sum;
    }
    __syncthreads();
    // rank-select: spa[p] = (#{q: patch[q] <= patch[p]} <= 98)
    if (t < PP) {
        float x = patch[t];
        int c = 0;
        for (int q = 0; q < PP; ++q) c += (patch[q] <= x) ? 1 : 0;
        spa[t] = (c <= NIDX) ? 1 : 0;
    }
    __syncthreads();
    // pass 3: masked sums
    int mode = *mode_p;
    const float* visb = vis + base + d0;
    float sava0 = 0.f, sava1 = 0.f, vpa0 = 0.f, vpa1 = 0.f;
    #pragma unroll 2
    for (int p = 0; p < PP; ++p) {
        unsigned v = *(const unsigned*)(pvb + (size_t)p * DD);
        float pv0 = bf16_tof((unsigned short)(v & 0xFFFFu));
        float pv1 = bf16_tof((unsigned short)(v >> 16));
        float sa0 = __expf(pv0 * pa0) * inv0;
        float sa1 = __expf(pv1 * pa1) * inv1;
        float2 vv = *(const float2*)(visb + (size_t)p * DD);
        bool m0, m1;
        size_t idx = base + (size_t)p * DD + d0;
        if (mode == 0) {
            int2 mi = *(const int2*)((const int*)rmask + idx);
            m0 = mi.x != 0; m1 = mi.y != 0;
        } else if (mode == 1) {
            float2 mf = *(const float2*)((const float*)rmask + idx);
            m0 = mf.x != 0.f; m1 = mf.y != 0.f;
        } else {
            const unsigned char* mb = (const unsigned char*)rmask + idx;
            m0 = mb[0] != 0; m1 = mb[1] != 0;
        }
        bool sp = spa[p];
        if (!(sp && m0)) { sava0 = fmaf(sa0, pv0, sava0); vpa0 = fmaf(sa0, vv.x, vpa0); }
        if (!(sp && m1)) { sava1 = fmaf(sa1, pv1, sava1); vpa1 = fmaf(sa1, vv.y, vpa1); }
    }
    *(float2*)&sav[(size_t)bt * DD + d0] = make_float2(sava0, sava1);
    *(float2*)&vpt[(size_t)bt * DD + d0] = make_float2(vpa0, vpa1);
}

// ---------------------------------------------------------------------------
// K4: temporal softmax + vp; vf; logits.  grid B, 768 threads
// ---------------------------------------------------------------------------
__global__ __launch_bounds__(768) void k_tail(
    const float* __restrict__ sav, const float* __restrict__ vpt,
    const float* __restrict__ pa, const float* __restrict__ af,
    const float* __restrict__ Wv, const float* __restrict__ bv,
    const float* __restrict__ Wc, const float* __restrict__ bc,
    float* __restrict__ out) {
    int b = blockIdx.x;
    int t = threadIdx.x;
    __shared__ float vp[DD];
    __shared__ float h[DD];
    float pav = pa[(size_t)b * DD + t];
    float x[TT];
    float mx = -1e30f;
    #pragma unroll
    for (int k = 0; k < TT; ++k) {
        x[k] = sav[((size_t)b * TT + k) * DD + t] * pav;
        mx = fmaxf(mx, x[k]);
    }
    float s = 0.f;
    #pragma unroll
    for (int k = 0; k < TT; ++k) { x[k] = __expf(x[k] - mx); s += x[k]; }
    float inv = 1.0f / s;
    float acc = 0.f;
    #pragma unroll
    for (int k = 0; k < TT; ++k)
        acc += x[k] * inv * vpt[((size_t)b * TT + k) * DD + t];
    vp[t] = acc;
    __syncthreads();
    float accv = bv[t];
    #pragma unroll 4
    for (int k = 0; k < DD; ++k) accv = fmaf(vp[k], Wv[(size_t)k * DD + t], accv);
    h[t] = fmaxf(accv, 0.f) + af[(size_t)b * DD + t];
    __syncthreads();
    if (t < NCLS) {
        float accc = bc[t];
        #pragma unroll 8
        for (int k = 0; k < DD; ++k) accc = fmaf(h[k], Wc[(size_t)k * NCLS + t], accc);
        out[(size_t)b * NCLS + t] = accc;
    }
}

// ---------------------------------------------------------------------------
extern "C" void kernel_launch(void* const* d_in, const int* in_sizes, int n_in,
                              void* d_out, int out_size, void* d_ws, size_t ws_size,
                              hipStream_t stream) {
    const float* visual = (const float*)d_in[0];
    const float* audio  = (const float*)d_in[1];
    const float* causal = (const float*)d_in[2];
    const void*  rmask  = d_in[3];
    const float* Wa   = (const float*)d_in[4];
    const float* ba   = (const float*)d_in[5];
    const float* Wv   = (const float*)d_in[6];
    const float* bv   = (const float*)d_in[7];
    const float* Waa  = (const float*)d_in[8];
    const float* baa  = (const float*)d_in[9];
    const float* Wav  = (const float*)d_in[10];
    const float* bav  = (const float*)d_in[11];
    const float* Wf   = (const float*)d_in[12];
    const float* bf   = (const float*)d_in[13];
    const float* Wf2  = (const float*)d_in[14];
    const float* bf2  = (const float*)d_in[15];
    const float* Wc   = (const float*)d_in[16];
    const float* bc   = (const float*)d_in[17];
    const float* cpar = (const float*)d_in[18];
    float* out = (float*)d_out;

    unsigned short* Wht = (unsigned short*)d_ws;             // 768*768 bf16
    unsigned short* Wlt = Wht + (size_t)DD * DD;             // 768*768 bf16
    float* tanhfeats = (float*)(Wlt + (size_t)DD * DD);      // B*M*D
    float* feats2    = tanhfeats + (size_t)BB * MM * DD;     // 320 (pad 512)
    float* paw       = feats2 + 512;                         // B*D
    float* afw       = paw + (size_t)BB * DD;                // B*D
    unsigned short* pv16 = (unsigned short*)(afw + (size_t)BB * DD); // B*T*P*D bf16
    float* savw      = (float*)(pv16 + (size_t)BB * TT * PP * DD);   // B*T*D
    float* vptw      = savw + (size_t)BB * TT * DD;          // B*T*D
    int*   modew     = (int*)(vptw + (size_t)BB * TT * DD);  // 1

    detect_mode<<<1, 256, 0, stream>>>((const unsigned int*)rmask, 16384, modew);
    k_split_w<<<dim3(24, 24), 256, 0, stream>>>(Wav, Wht, Wlt);
    k_feats<<<dim3(BB, 3), 768, 0, stream>>>(causal, Wf, bf, Wf2, bf2, tanhfeats, feats2);
    k_audio2<<<BB, 768, 0, stream>>>(causal, audio, tanhfeats, feats2, cpar,
                                     Waa, baa, Wa, ba, paw, afw);
    k_pv_mfma<<<2352, 256, 0, stream>>>(visual, Wht, Wlt, bav, pv16);
    k_spatial<<<BB * TT, 384, 0, stream>>>(pv16, visual, rmask, modew, paw, savw, vptw);
    k_tail<<<BB, 768, 0, stream>>>(savw, vptw, paw, afw, Wv, bv, Wc, bc, out);
}

// Round 4
// 688.518 us; speedup vs baseline: 2.2274x; 1.0969x over previous
//
#include <hip/hip_runtime.h>
#include <math.h>

#define BB 32
#define TT 8
#define PP 196
#define DD 768
#define MM 10
#define NCLS 100
#define NIDX 98

typedef __attribute__((ext_vector_type(8))) short short8v;
typedef __attribute__((ext_vector_type(4))) float float4v;

__device__ __forceinline__ float fast_tanh(float x) {
    float e = __expf(2.0f * x);
    return 1.0f - 2.0f / (e + 1.0f);
}
__device__ __forceinline__ unsigned short bf16_rtne(float x) {
    unsigned u = __float_as_uint(x);
    return (unsigned short)((u + 0x7FFFu + ((u >> 16) & 1u)) >> 16);
}
__device__ __forceinline__ float bf16_tof(unsigned short h) {
    return __uint_as_float(((unsigned)h) << 16);
}

// ---------------------------------------------------------------------------
// mask dtype detection: 0 = int32 {0,1}, 1 = float32 {0,1.0f}, 2 = bytes
// ---------------------------------------------------------------------------
__global__ void detect_mode(const unsigned int* __restrict__ w, int n, int* __restrict__ mode) {
    __shared__ int f_ni, f_nf;
    if (threadIdx.x == 0) { f_ni = 0; f_nf = 0; }
    __syncthreads();
    int ni = 0, nf = 0;
    for (int i = threadIdx.x; i < n; i += blockDim.x) {
        unsigned int x = w[i];
        ni |= (x > 1u) ? 1 : 0;
        nf |= (x != 0u && x != 0x3F800000u) ? 1 : 0;
    }
    if (ni) atomicOr(&f_ni, 1);
    if (nf) atomicOr(&f_nf, 1);
    __syncthreads();
    if (threadIdx.x == 0) *mode = f_ni ? (f_nf ? 2 : 1) : 0;
}

// ---------------------------------------------------------------------------
// Wav transpose + rtne: Wht[n][k] bf16
// ---------------------------------------------------------------------------
__global__ __launch_bounds__(256) void k_split_w(const float* __restrict__ W,
    unsigned short* __restrict__ ht) {
    __shared__ float tile[32][33];
    int bn = blockIdx.x * 32;
    int bk = blockIdx.y * 32;
    int tx = threadIdx.x & 31, ty = threadIdx.x >> 5;
    #pragma unroll
    for (int i = 0; i < 4; ++i)
        tile[ty + i * 8][tx] = W[(size_t)(bk + ty + i * 8) * DD + bn + tx];
    __syncthreads();
    #pragma unroll
    for (int i = 0; i < 4; ++i) {
        int n = bn + ty + i * 8, k = bk + tx;
        ht[(size_t)n * DD + k] = bf16_rtne(tile[tx][ty + i * 8]);
    }
}

// ---------------------------------------------------------------------------
// K0: feats = tanh(causal @ Wf + bf); feats2 = causal @ Wf2 + bf2
// grid (B, 3): m-groups {3,3,4}, 768 threads
// ---------------------------------------------------------------------------
__global__ __launch_bounds__(768) void k_feats(
    const float* __restrict__ causal, const float* __restrict__ Wf,
    const float* __restrict__ bf, const float* __restrict__ Wf2,
    const float* __restrict__ bf2, float* __restrict__ tanhfeats,
    float* __restrict__ feats2) {
    int b = blockIdx.x;
    int m0 = blockIdx.y * 3;
    int mcnt = (blockIdx.y == 2) ? 4 : 3;
    int t = threadIdx.x;
    __shared__ float cs[4][DD];
    __shared__ float red[4][12];
    for (int m = 0; m < mcnt; ++m)
        cs[m][t] = causal[((size_t)b * MM + m0 + m) * DD + t];
    if (mcnt == 3) cs[3][t] = 0.f;
    __syncthreads();
    float w2 = Wf2[t];
    int wave = t >> 6, lane = t & 63;
    for (int m = 0; m < mcnt; ++m) {
        float p = cs[m][t] * w2;
        #pragma unroll
        for (int o = 32; o > 0; o >>= 1) p += __shfl_down(p, o);
        if (lane == 0) red[m][wave] = p;
    }
    __syncthreads();
    if (t < mcnt) {
        float s = 0.f;
        #pragma unroll
        for (int wv = 0; wv < 12; ++wv) s += red[t][wv];
        feats2[b * MM + m0 + t] = s + bf2[0];
    }
    float acc[4];
    #pragma unroll
    for (int m = 0; m < 4; ++m) acc[m] = bf[t];
    #pragma unroll 4
    for (int k = 0; k < DD; ++k) {
        float wv = Wf[(size_t)k * DD + t];
        #pragma unroll
        for (int m = 0; m < 4; ++m) acc[m] = fmaf(cs[m][k], wv, acc[m]);
    }
    for (int m = 0; m < mcnt; ++m)
        tanhfeats[((size_t)b * MM + m0 + m) * DD + t] = fast_tanh(acc[m]);
}

// ---------------------------------------------------------------------------
// K1: softmax_m, ci, audio2, pa, af.  grid B, 768 threads
// ---------------------------------------------------------------------------
__global__ __launch_bounds__(768) void k_audio2(
    const float* __restrict__ causal, const float* __restrict__ audio,
    const float* __restrict__ tanhfeats, const float* __restrict__ feats2,
    const float* __restrict__ cparam,
    const float* __restrict__ Waa, const float* __restrict__ baa,
    const float* __restrict__ Wa, const float* __restrict__ ba,
    float* __restrict__ pa, float* __restrict__ af) {
    int b = blockIdx.x;
    int t = threadIdx.x;
    __shared__ float a2[DD];
    float cp = 1.0f / (1.0f + __expf(-cparam[0]));
    float tf[MM];
    float mx = -1e30f;
    #pragma unroll
    for (int m = 0; m < MM; ++m) {
        tf[m] = tanhfeats[((size_t)b * MM + m) * DD + t];
        mx = fmaxf(mx, tf[m]);
    }
    float s = 0.f;
    #pragma unroll
    for (int m = 0; m < MM; ++m) { tf[m] = __expf(tf[m] - mx); s += tf[m]; }
    float inv = 1.0f / s;
    float ci = 0.f;
    #pragma unroll
    for (int m = 0; m < MM; ++m)
        ci += feats2[b * MM + m] * (tf[m] * inv) * causal[((size_t)b * MM + m) * DD + t];
    a2[t] = cp * ci + audio[(size_t)b * DD + t];
    __syncthreads();
    float accp = baa[t], acca = ba[t];
    #pragma unroll 8
    for (int k = 0; k < DD; ++k) {
        float av = a2[k];
        accp = fmaf(av, Waa[(size_t)k * DD + t], accp);
        acca = fmaf(av, Wa[(size_t)k * DD + t], acca);
    }
    pa[(size_t)b * DD + t] = fast_tanh(accp);
    af[(size_t)b * DD + t] = fmaxf(acca, 0.f);
}

// ---------------------------------------------------------------------------
// K2: pv16 = bf16(tanh(vis @ Wav + bav)), 2-term split MFMA:
// C = (Ah+Al)*Bh, Bh = rtne(Wav). LDS 48KB -> 3 blocks/CU.
// ---------------------------------------------------------------------------
__global__ __launch_bounds__(256, 3) void k_pv_mfma(
    const float* __restrict__ vis, const unsigned short* __restrict__ Wht,
    const float* __restrict__ bav, unsigned short* __restrict__ pv16)
{
    __shared__ unsigned short Ah[128 * 64];
    __shared__ unsigned short Al[128 * 64];
    __shared__ unsigned short Bh[128 * 64];
    int wg = blockIdx.x;
    int lin = (wg & 7) * 294 + (wg >> 3);   // bijective XCD swizzle (2352%8==0)
    int mt = lin / 6, nt = lin % 6;
    int i0 = mt * 128, n0 = nt * 128;
    int t = threadIdx.x, w = t >> 6, l = t & 63;
    int wm = (w >> 1) * 64, wn = (w & 1) * 64;

    float4v zero4 = {0.f, 0.f, 0.f, 0.f};
    float4v acc[4][4];
    #pragma unroll
    for (int a = 0; a < 4; ++a)
        #pragma unroll
        for (int b = 0; b < 4; ++b) acc[a][b] = zero4;

    // B staging: call j -> wave w covers Bh bytes [(w*4+j)*1024, +1024)
    int brow[4], bcs[4];
    #pragma unroll
    for (int j = 0; j < 4; ++j) {
        int row = (w * 4 + j) * 8 + (l >> 3);
        brow[j] = row;
        bcs[j] = (l & 7) ^ (row & 7);
    }
    // A staging: thread t covers row t>>1, chunks (t&1)*4..+3
    int arow = t >> 1, acb = (t & 1) * 4;
    const float* avbase = vis + (size_t)(i0 + arow) * DD + acb * 8;
    int aoff[4];
    #pragma unroll
    for (int c4 = 0; c4 < 4; ++c4) {
        int c = acb + c4;
        aoff[c4] = arow * 64 + ((c ^ (arow & 7)) * 8);
    }

    float f[32];
    #pragma unroll
    for (int q = 0; q < 8; ++q)
        *(float4*)&f[q * 4] = *(const float4*)(avbase + q * 4);

    for (int wnd = 0; wnd < 12; ++wnd) {
        __syncthreads();   // previous window's compute done; LDS reusable
        unsigned short hv[32], lv[32];
        #pragma unroll
        for (int i = 0; i < 32; ++i) {
            unsigned short h = (unsigned short)(__float_as_uint(f[i]) >> 16);
            hv[i] = h;
            lv[i] = bf16_rtne(f[i] - bf16_tof(h));
        }
        #pragma unroll
        for (int c4 = 0; c4 < 4; ++c4) {
            *(short8v*)&Ah[aoff[c4]] = *(const short8v*)&hv[c4 * 8];
            *(short8v*)&Al[aoff[c4]] = *(const short8v*)&lv[c4 * 8];
        }
        int kw = wnd * 64;
        #pragma unroll
        for (int j = 0; j < 4; ++j) {
            size_t off = (size_t)(n0 + brow[j]) * DD + kw + bcs[j] * 8;
            __builtin_amdgcn_global_load_lds(
                (const __attribute__((address_space(1))) unsigned int*)(Wht + off),
                (__attribute__((address_space(3))) unsigned int*)&Bh[(w * 4 + j) * 512],
                16, 0, 0);
        }
        __syncthreads();
        // prefetch next window's A f32 (hidden under MFMAs)
        if (wnd < 11) {
            const float* ap = avbase + (wnd + 1) * 64;
            #pragma unroll
            for (int q = 0; q < 8; ++q)
                *(float4*)&f[q * 4] = *(const float4*)(ap + q * 4);
        }
        #pragma unroll
        for (int kk = 0; kk < 2; ++kk) {
            short8v ahf[4], alf[4], bhf[4];
            #pragma unroll
            for (int mr = 0; mr < 4; ++mr) {
                int row = wm + mr * 16 + (l & 15);
                int c = kk * 4 + (l >> 4);
                int off = row * 64 + ((c ^ (row & 7)) * 8);
                ahf[mr] = *(const short8v*)&Ah[off];
                alf[mr] = *(const short8v*)&Al[off];
            }
            #pragma unroll
            for (int nc = 0; nc < 4; ++nc) {
                int row = wn + nc * 16 + (l & 15);
                int c = kk * 4 + (l >> 4);
                int off = row * 64 + ((c ^ (row & 7)) * 8);
                bhf[nc] = *(const short8v*)&Bh[off];
            }
            #pragma unroll
            for (int mr = 0; mr < 4; ++mr)
                #pragma unroll
                for (int nc = 0; nc < 4; ++nc) {
                    acc[mr][nc] = __builtin_amdgcn_mfma_f32_16x16x32_bf16(
                        ahf[mr], bhf[nc], acc[mr][nc], 0, 0, 0);
                    acc[mr][nc] = __builtin_amdgcn_mfma_f32_16x16x32_bf16(
                        alf[mr], bhf[nc], acc[mr][nc], 0, 0, 0);
                }
        }
    }
    // epilogue: col = lane&15 (+16nc), row = (lane>>4)*4 + v (+16mr)
    #pragma unroll
    for (int nc = 0; nc < 4; ++nc) {
        int col = n0 + wn + nc * 16 + (l & 15);
        float bias = bav[col];
        #pragma unroll
        for (int mr = 0; mr < 4; ++mr) {
            int row0 = i0 + wm + mr * 16 + ((l >> 4) << 2);
            #pragma unroll
            for (int v = 0; v < 4; ++v)
                pv16[(size_t)(row0 + v) * DD + col] =
                    bf16_rtne(fast_tanh(acc[mr][nc][v] + bias));
        }
    }
}

// ---------------------------------------------------------------------------
// K3: per (b,t): spatial softmax (no max: |pv*pa|<1), patch sums, rank-select,
// masked sums. 768 threads (12 waves/CU), 1 d per thread.
// ---------------------------------------------------------------------------
__global__ __launch_bounds__(768) void k_spatial(
    const unsigned short* __restrict__ pv16, const float* __restrict__ vis,
    const void* __restrict__ rmask, const int* __restrict__ mode_p,
    const float* __restrict__ pa,
    float* __restrict__ sav, float* __restrict__ vpt) {
    int bt = blockIdx.x;
    int b = bt >> 3;
    size_t base = (size_t)bt * PP * DD;
    __shared__ float2 pi[DD];         // {pa_d, inv_d}
    __shared__ float patch[PP];
    __shared__ unsigned char spa[PP];
    int t = threadIdx.x;
    float pav = pa[(size_t)b * DD + t];
    const unsigned short* pvb = pv16 + base + t;
    // pass 1: column sums of exp
    float s = 0.f;
    #pragma unroll 4
    for (int p = 0; p < PP; ++p)
        s += __expf(bf16_tof(pvb[(size_t)p * DD]) * pav);
    float inv = 1.0f / s;
    pi[t] = make_float2(pav, inv);
    __syncthreads();
    // pass 2: patch[p] = sum_d sattn[p,d]
    int wave = t >> 6, lane = t & 63;
    for (int p = wave; p < PP; p += 12) {
        const unsigned short* row = pv16 + base + (size_t)p * DD;
        float sum = 0.f;
        #pragma unroll
        for (int c = lane; c < DD; c += 64) {
            float2 q = pi[c];
            sum += __expf(bf16_tof(row[c]) * q.x) * q.y;
        }
        #pragma unroll
        for (int o = 32; o > 0; o >>= 1) sum += __shfl_down(sum, o);
        if (lane == 0) patch[p] = sum;
    }
    __syncthreads();
    // rank-select: spa[p] = (#{q: patch[q] <= patch[p]} <= 98)
    if (t < PP) {
        float x = patch[t];
        int c = 0;
        for (int q = 0; q < PP; ++q) c += (patch[q] <= x) ? 1 : 0;
        spa[t] = (c <= NIDX) ? 1 : 0;
    }
    __syncthreads();
    // pass 3: masked sums (mode hoisted out of loop)
    int mode = *mode_p;
    const float* visb = vis + base + t;
    float sava = 0.f, vpa = 0.f;
    if (mode == 0) {
        const int* mb = (const int*)rmask + base + t;
        #pragma unroll 4
        for (int p = 0; p < PP; ++p) {
            float pvv = bf16_tof(pvb[(size_t)p * DD]);
            float sa = __expf(pvv * pav) * inv;
            bool km = !(spa[p] && (mb[(size_t)p * DD] != 0));
            if (km) { sava = fmaf(sa, pvv, sava); vpa = fmaf(sa, visb[(size_t)p * DD], vpa); }
        }
    } else if (mode == 1) {
        const float* mb = (const float*)rmask + base + t;
        #pragma unroll 4
        for (int p = 0; p < PP; ++p) {
            float pvv = bf16_tof(pvb[(size_t)p * DD]);
            float sa = __expf(pvv * pav) * inv;
            bool km = !(spa[p] && (mb[(size_t)p * DD] != 0.f));
            if (km) { sava = fmaf(sa, pvv, sava); vpa = fmaf(sa, visb[(size_t)p * DD], vpa); }
        }
    } else {
        const unsigned char* mb = (const unsigned char*)rmask + base + t;
        #pragma unroll 4
        for (int p = 0; p < PP; ++p) {
            float pvv = bf16_tof(pvb[(size_t)p * DD]);
            float sa = __expf(pvv * pav) * inv;
            bool km = !(spa[p] && (mb[(size_t)p * DD] != 0));
            if (km) { sava = fmaf(sa, pvv, sava); vpa = fmaf(sa, visb[(size_t)p * DD], vpa); }
        }
    }
    sav[(size_t)bt * DD + t] = sava;
    vpt[(size_t)bt * DD + t] = vpa;
}

// ---------------------------------------------------------------------------
// K4: temporal softmax + vp; vf; logits.  grid B, 768 threads
// ---------------------------------------------------------------------------
__global__ __launch_bounds__(768) void k_tail(
    const float* __restrict__ sav, const float* __restrict__ vpt,
    const float* __restrict__ pa, const float* __restrict__ af,
    const float* __restrict__ Wv, const float* __restrict__ bv,
    const float* __restrict__ Wc, const float* __restrict__ bc,
    float* __restrict__ out) {
    int b = blockIdx.x;
    int t = threadIdx.x;
    __shared__ float vp[DD];
    __shared__ float h[DD];
    float pav = pa[(size_t)b * DD + t];
    float x[TT];
    float mx = -1e30f;
    #pragma unroll
    for (int k = 0; k < TT; ++k) {
        x[k] = sav[((size_t)b * TT + k) * DD + t] * pav;
        mx = fmaxf(mx, x[k]);
    }
    float s = 0.f;
    #pragma unroll
    for (int k = 0; k < TT; ++k) { x[k] = __expf(x[k] - mx); s += x[k]; }
    float inv = 1.0f / s;
    float acc = 0.f;
    #pragma unroll
    for (int k = 0; k < TT; ++k)
        acc += x[k] * inv * vpt[((size_t)b * TT + k) * DD + t];
    vp[t] = acc;
    __syncthreads();
    float accv = bv[t];
    #pragma unroll 8
    for (int k = 0; k < DD; ++k) accv = fmaf(vp[k], Wv[(size_t)k * DD + t], accv);
    h[t] = fmaxf(accv, 0.f) + af[(size_t)b * DD + t];
    __syncthreads();
    if (t < NCLS) {
        float accc = bc[t];
        #pragma unroll 8
        for (int k = 0; k < DD; ++k) accc = fmaf(h[k], Wc[(size_t)k * NCLS + t], accc);
        out[(size_t)b * NCLS + t] = accc;
    }
}

// ---------------------------------------------------------------------------
extern "C" void kernel_launch(void* const* d_in, const int* in_sizes, int n_in,
                              void* d_out, int out_size, void* d_ws, size_t ws_size,
                              hipStream_t stream) {
    const float* visual = (const float*)d_in[0];
    const float* audio  = (const float*)d_in[1];
    const float* causal = (const float*)d_in[2];
    const void*  rmask  = d_in[3];
    const float* Wa   = (const float*)d_in[4];
    const float* ba   = (const float*)d_in[5];
    const float* Wv   = (const float*)d_in[6];
    const float* bv   = (const float*)d_in[7];
    const float* Waa  = (const float*)d_in[8];
    const float* baa  = (const float*)d_in[9];
    const float* Wav  = (const float*)d_in[10];
    const float* bav  = (const float*)d_in[11];
    const float* Wf   = (const float*)d_in[12];
    const float* bf   = (const float*)d_in[13];
    const float* Wf2  = (const float*)d_in[14];
    const float* bf2  = (const float*)d_in[15];
    const float* Wc   = (const float*)d_in[16];
    const float* bc   = (const float*)d_in[17];
    const float* cpar = (const float*)d_in[18];
    float* out = (float*)d_out;

    unsigned short* Wht = (unsigned short*)d_ws;             // 768*768 bf16
    float* tanhfeats = (float*)(Wht + (size_t)DD * DD);      // B*M*D
    float* feats2    = tanhfeats + (size_t)BB * MM * DD;     // 320 (pad 512)
    float* paw       = feats2 + 512;                         // B*D
    float* afw       = paw + (size_t)BB * DD;                // B*D
    unsigned short* pv16 = (unsigned short*)(afw + (size_t)BB * DD); // B*T*P*D bf16
    float* savw      = (float*)(pv16 + (size_t)BB * TT * PP * DD);   // B*T*D
    float* vptw      = savw + (size_t)BB * TT * DD;          // B*T*D
    int*   modew     = (int*)(vptw + (size_t)BB * TT * DD);  // 1

    detect_mode<<<1, 256, 0, stream>>>((const unsigned int*)rmask, 16384, modew);
    k_split_w<<<dim3(24, 24), 256, 0, stream>>>(Wav, Wht);
    k_feats<<<dim3(BB, 3), 768, 0, stream>>>(causal, Wf, bf, Wf2, bf2, tanhfeats, feats2);
    k_audio2<<<BB, 768, 0, stream>>>(causal, audio, tanhfeats, feats2, cpar,
                                     Waa, baa, Wa, ba, paw, afw);
    k_pv_mfma<<<2352, 256, 0, stream>>>(visual, Wht, bav, pv16);
    k_spatial<<<BB * TT, 768, 0, stream>>>(pv16, visual, rmask, modew, paw, savw, vptw);
    k_tail<<<BB, 768, 0, stream>>>(savw, vptw, paw, afw, Wv, bv, Wc, bc, out);
}